// Round 4
// baseline (108.524 us; speedup 1.0000x reference)
//
#include <hip/hip_runtime.h>

// QueryAndGroupRRI: B=4, N=16384, M=2048, nsample=32, radius=0.1
// Inputs (float32): xyz (4,16384,3), new_xyz (4,2048,3)
// Output (float32): (4, 33, 2048, 32)  [dis_sort rows 0..31, grouped_r row 32]
//
// R13: calibrated model: total = ~32us harness overhead + query + build.
// (a) Query: 1 query per 64-lane wave (was 2/wave). 8192 waves -> 32
//     waves/CU (100% occ cap, was 16) and phase-1 rounds halve per wave.
//     Phase 2 duplicated across both 32-lane halves (identical data; idle
//     lanes otherwise), global stores guarded to half 0. Phase-2 math is
//     byte-identical to the verified R8 code (XOR shuffles <=16 stay in-half).
// (b) Build: 512 blocks x 512 thr (was 128x1024 = half chip idle). Full-chip,
//     2 blocks/CU; redundant full-batch histogram per block (L2-resident,
//     ~201MB L2 traffic ~ 6us). Same verified triplet float4 decode as R12.

#define BB 4
#define NN 16384
#define MM 2048
#define NS 32
#define R2 0.01f
#define GZ 20          // z slabs
#define NCELL 2000     // 10*10*20
#define CPAD 2048
#define HCAP 128       // per-query hit cap (lambda~68, +7sigma safe)

// ws layout (off table + pts; legacy offsets kept stable)
#define WS_PTS_OFF (96 * 1024)
#define WS_NEED (WS_PTS_OFF + (size_t)BB * NN * 16)

__device__ __forceinline__ int cell_of(float x, float y, float z) {
    int ci = (int)(x * 10.0f); ci = ci < 0 ? 0 : (ci > 9 ? 9 : ci);
    int cj = (int)(y * 10.0f); cj = cj < 0 ? 0 : (cj > 9 ? 9 : cj);
    int ck = (int)(z * 20.0f); ck = ck < 0 ? 0 : (ck > 19 ? 19 : ck);
    return (ci * 10 + cj) * GZ + ck;
}

// ---- R13 build: one dispatch, no grid sync, full chip ----
// grid = 512 blocks x 512 thr. Block (b, r): full histogram of batch b in LDS
// (redundant, L2-resident), local exclusive scan, scatter cells
// [r*16, r*16+16). Points read as 3x float4 = 4 points/thread/iteration.
__global__ __launch_bounds__(512) void k_build_part(const float* __restrict__ xyz,
                                                    int* __restrict__ off,
                                                    float4* __restrict__ pts) {
    __shared__ int hist[CPAD];    // 8 KB: counts, then running cur offsets
    __shared__ int wsum[8];

    const int b = blockIdx.x >> 7;    // 128 blocks per batch
    const int r = blockIdx.x & 127;   // 16 cells per block
    const int t = threadIdx.x;
    const int lane = t & 63, wid = t >> 6;
    const float4* __restrict__ xb4 = (const float4*)(xyz + (size_t)b * NN * 3);
    float4* __restrict__ ptsb = pts + (size_t)b * NN;

    #pragma unroll
    for (int j = 0; j < 4; ++j) hist[t + j * 512] = 0;
    __syncthreads();

    // pass 1: full-batch histogram; 4 pts/thread/iter via 3 float4 loads
    #pragma unroll
    for (int it = 0; it < 8; ++it) {
        const int f = (it * 512 + t) * 3;
        float4 a = xb4[f];
        float4 g = xb4[f + 1];
        float4 c = xb4[f + 2];
        atomicAdd(&hist[cell_of(a.x, a.y, a.z)], 1);
        atomicAdd(&hist[cell_of(a.w, g.x, g.y)], 1);
        atomicAdd(&hist[cell_of(g.z, g.w, c.x)], 1);
        atomicAdd(&hist[cell_of(c.y, c.z, c.w)], 1);
    }
    __syncthreads();

    // exclusive scan of hist[0..2047]: 4 cells/thread, wave shfl scan
    const int base = t * 4;
    int v[4]; int s = 0;
    #pragma unroll
    for (int j = 0; j < 4; ++j) { v[j] = hist[base + j]; s += v[j]; }
    int xs = s;
    #pragma unroll
    for (int o = 1; o < 64; o <<= 1) {
        int u = __shfl_up(xs, o);
        if (lane >= o) xs += u;
    }
    if (lane == 63) wsum[wid] = xs;
    __syncthreads();
    int pre = 0;
    #pragma unroll
    for (int i2 = 0; i2 < 8; ++i2) pre += (i2 < wid) ? wsum[i2] : 0;
    int run = pre + xs - s;                      // exclusive prefix of this thread
    #pragma unroll
    for (int j = 0; j < 4; ++j) {
        if (r == 0) off[b * CPAD + base + j] = run;   // one block/batch writes off
        hist[base + j] = run;                         // hist becomes cur
        run += v[j];
    }
    __syncthreads();

    // pass 2: scatter own cell range from LDS cur (no global atomics)
    const int clo = r * 16, chi = clo + 16;
    #pragma unroll
    for (int it = 0; it < 8; ++it) {
        const int f = (it * 512 + t) * 3;
        float4 a = xb4[f];
        float4 g = xb4[f + 1];
        float4 c = xb4[f + 2];
        const int i0 = (it * 512 + t) * 4;
        float X[4] = {a.x, a.w, g.z, c.y};
        float Y[4] = {a.y, g.x, g.w, c.z};
        float Z[4] = {a.z, g.y, c.x, c.w};
        #pragma unroll
        for (int k = 0; k < 4; ++k) {
            int cc = cell_of(X[k], Y[k], Z[k]);
            if (cc >= clo && cc < chi) {
                int pos = atomicAdd(&hist[cc], 1);
                ptsb[pos] = make_float4(X[k], Y[k], Z[k], __int_as_float(i0 + k));
            }
        }
    }
}

// ---- R13 query: 1 query per 64-lane wave; phase-2 math identical to R8 ----
__global__ __launch_bounds__(256) void qgr_grid_kernel(
    const float* __restrict__ xyz,
    const float* __restrict__ nxyz,
    const int* __restrict__ offi,
    const float4* __restrict__ pts,
    float* __restrict__ out) {

    __shared__ float4 s_hit[4][HCAP];   // 8 KB: hit (x,y,z,idx-bits)
    __shared__ float4 s_sel[4][NS];     // 2 KB: selected 32, slot order

    const int lane = threadIdx.x & 63;
    const int w = threadIdx.x >> 6;
    const int sub = lane & 31;
    const int half = lane >> 5;
    const int q = blockIdx.x * 4 + w;          // one query per wave
    const int b = q >> 11;

    const float* xb = xyz + (size_t)b * NN * 3;
    const float* nq = nxyz + (size_t)q * 3;
    const float ccx = nq[0], ccy = nq[1], ccz = nq[2];
    const unsigned long long lmask = (1ull << lane) - 1ull;

    const int* offb = offi + b * CPAD;
    const float4* ptsb = pts + (size_t)b * NN;

    // ---- phase 1: full-wave scan for this wave's single query ----
    int hits = 0;
    {
        int ci0 = (int)(ccx * 10.0f); ci0 = ci0 < 0 ? 0 : (ci0 > 9 ? 9 : ci0);
        int cj0 = (int)(ccy * 10.0f); cj0 = cj0 < 0 ? 0 : (cj0 > 9 ? 9 : cj0);
        int ck0 = (int)(ccz * 20.0f); ck0 = ck0 < 0 ? 0 : (ck0 > 19 ? 19 : ck0);
        int zlo = ck0 > 2 ? ck0 - 2 : 0;
        int zhi = ck0 < 17 ? ck0 + 2 : 19;

        int rs[9], rl[9];
        #pragma unroll
        for (int r = 0; r < 9; ++r) { rs[r] = 0; rl[r] = 0; }
        int nr = 0;
        #pragma unroll
        for (int di = -1; di <= 1; ++di) {
            int ii = ci0 + di; if ((unsigned)ii > 9u) continue;
            #pragma unroll
            for (int dj = -1; dj <= 1; ++dj) {
                int jj = cj0 + dj; if ((unsigned)jj > 9u) continue;
                int base2 = (ii * 10 + jj) * GZ;
                int s0 = offb[base2 + zlo];
                int e0 = offb[base2 + zhi + 1];
                int len = e0 - s0;
                if (len > 0) { rs[nr] = s0; rl[nr] = len; ++nr; }
            }
        }

        float4 P[9];
        #pragma unroll
        for (int r = 0; r < 9; ++r) {
            int a = (lane < rl[r]) ? (rs[r] + lane) : 0;
            P[r] = ptsb[a];
        }

        #pragma unroll
        for (int r = 0; r < 9; ++r) {
            float dx = __fsub_rn(ccx, P[r].x);
            float dy = __fsub_rn(ccy, P[r].y);
            float dz = __fsub_rn(ccz, P[r].z);
            float d2 = __fadd_rn(__fadd_rn(__fmul_rn(dx, dx), __fmul_rn(dy, dy)),
                                 __fmul_rn(dz, dz));
            bool hit = (lane < rl[r]) && (d2 < R2);
            unsigned long long bal = __ballot(hit);
            if (bal) {
                int rank = __popcll(bal & lmask);
                int slot = hits + rank;
                if (hit && slot < HCAP) s_hit[w][slot] = P[r];
                hits += __popcll(bal);
            }
        }
        for (int r = 0; r < nr; ++r) {           // rare: ranges > 64
            for (int t0 = 64; t0 < rl[r]; t0 += 64) {
                int t = t0 + lane;
                bool act = t < rl[r];
                float4 Q = ptsb[rs[r] + (act ? t : 0)];
                float dx = __fsub_rn(ccx, Q.x);
                float dy = __fsub_rn(ccy, Q.y);
                float dz = __fsub_rn(ccz, Q.z);
                float d2 = __fadd_rn(__fadd_rn(__fmul_rn(dx, dx), __fmul_rn(dy, dy)),
                                     __fmul_rn(dz, dz));
                bool hit = act && (d2 < R2);
                unsigned long long bal = __ballot(hit);
                if (bal) {
                    int rank = __popcll(bal & lmask);
                    int slot = hits + rank;
                    if (hit && slot < HCAP) s_hit[w][slot] = Q;
                    hits += __popcll(bal);
                }
            }
        }
    }

    // ---- phase 2: both 32-lane halves compute identically; half 0 stores ----
    const int cap = hits < HCAP ? hits : HCAP;

    // 128-elem bitonic in 4 regs x 32 lanes (verified R7); key = idx<<8 | slot
    int key[4];
    #pragma unroll
    for (int r = 0; r < 4; ++r) {
        int e = r * 32 + sub;
        int idx_e = __float_as_int(s_hit[w][e].w);
        key[r] = (e < cap) ? ((idx_e << 8) | e) : 0x7fffffff;
    }

    #pragma unroll
    for (int k = 2; k <= 16; k <<= 1) {
        #pragma unroll
        for (int j = k >> 1; j > 0; j >>= 1) {
            bool lower = (sub & j) == 0;
            bool asc = (sub & k) == 0;
            bool keepmin = (lower == asc);
            #pragma unroll
            for (int r = 0; r < 4; ++r) {
                int p = __shfl_xor(key[r], j);
                key[r] = keepmin ? min(key[r], p) : max(key[r], p);
            }
        }
    }
    #pragma unroll
    for (int j = 16; j > 0; j >>= 1) {
        bool lower = (sub & j) == 0;
        #pragma unroll
        for (int r = 0; r < 4; ++r) {
            int p = __shfl_xor(key[r], j);
            bool asc = (r & 1) == 0;
            key[r] = (lower == asc) ? min(key[r], p) : max(key[r], p);
        }
    }
    {
        int t0 = min(key[0], key[1]); key[1] = max(key[0], key[1]); key[0] = t0;
        int t2 = max(key[2], key[3]); key[3] = min(key[2], key[3]); key[2] = t2;
    }
    #pragma unroll
    for (int j = 16; j > 0; j >>= 1) {
        bool lower = (sub & j) == 0;
        #pragma unroll
        for (int r = 0; r < 4; ++r) {
            int p = __shfl_xor(key[r], j);
            bool asc = (r & 2) == 0;
            key[r] = (lower == asc) ? min(key[r], p) : max(key[r], p);
        }
    }
    {
        int t0 = min(key[0], key[2]); key[2] = max(key[0], key[2]); key[0] = t0;
        int t1 = min(key[1], key[3]); key[3] = max(key[1], key[3]); key[1] = t1;
        t0 = min(key[0], key[1]); key[1] = max(key[0], key[1]); key[0] = t0;
        t1 = min(key[2], key[3]); key[3] = max(key[2], key[3]); key[2] = t1;
    }
    #pragma unroll
    for (int j = 16; j > 0; j >>= 1) {
        bool lower = (sub & j) == 0;
        #pragma unroll
        for (int r = 0; r < 4; ++r) {
            int p = __shfl_xor(key[r], j);
            key[r] = lower ? min(key[r], p) : max(key[r], p);
        }
    }

    // fetch selected points (smallest 32 indices, ascending), pad with slot 0
    const int found = hits < NS ? hits : NS;
    float4 sel = make_float4(0.f, 0.f, 0.f, 0.f);
    if (sub < found) sel = s_hit[w][key[0] & 0xFF];
    float p0x, p0y, p0z;
    if (found == 0) { p0x = xb[0]; p0y = xb[1]; p0z = xb[2]; }
    else {
        // lane (half*32) holds the first selected point of this half's copy
        p0x = __shfl(sel.x, half << 5);
        p0y = __shfl(sel.y, half << 5);
        p0z = __shfl(sel.z, half << 5);
    }
    if (sub >= found) { sel.x = p0x; sel.y = p0y; sel.z = p0z; }
    const float hx = sel.x, hy = sel.y, hz = sel.z;

    // stage selected pts for broadcast reads (both halves write same values)
    s_sel[w][sub] = sel;

    // dis column j=sub via ds_read_b128 broadcasts (exact np op order)
    float v[NS];
    #pragma unroll
    for (int ii = 0; ii < NS; ++ii) {
        float4 B = s_sel[w][ii];
        float dx = __fsub_rn(B.x, hx);
        float dy = __fsub_rn(B.y, hy);
        float dz = __fsub_rn(B.z, hz);
        v[ii] = sqrtf(__fadd_rn(__fadd_rn(__fmul_rn(dx, dx), __fmul_rn(dy, dy)),
                                __fmul_rn(dz, dz)));
    }

    // row-sub sum in numpy pairwise-8 order; half-local argmax, first-occurrence
    float r8[8];
    #pragma unroll
    for (int t = 0; t < 8; ++t) {
        r8[t] = __fadd_rn(__fadd_rn(__fadd_rn(v[t], v[t + 8]), v[t + 16]), v[t + 24]);
    }
    float mv = __fadd_rn(__fadd_rn(__fadd_rn(r8[0], r8[1]), __fadd_rn(r8[2], r8[3])),
                         __fadd_rn(__fadd_rn(r8[4], r8[5]), __fadd_rn(r8[6], r8[7])));
    int mi = sub;
    #pragma unroll
    for (int off = 1; off < 32; off <<= 1) {
        float ov = __shfl_xor(mv, off);
        int oi = __shfl_xor(mi, off);
        if (ov > mv || (ov == mv && oi < mi)) { mv = ov; mi = oi; }
    }

    float4 T = s_sel[w][mi];
    const float tx = T.x, ty = T.y, tz = T.z;

    float ux = ccy * tz - ccz * ty, uy = ccz * tx - ccx * tz, uz = ccx * ty - ccy * tx;
    float vx = uy * ccz - uz * ccy, vy = uz * ccx - ux * ccz, vz = ux * ccy - uy * ccx;
    float vn = fmaxf(sqrtf(vx * vx + vy * vy + vz * vz), 1e-37f);
    float tnx = vx / vn, tny = vy / vn, tnz = vz / vn;

    float nrm = sqrtf(ccx * ccx + ccy * ccy + ccz * ccz);
    float dn = nrm + 1e-8f;
    float nnx = ccx / dn, nny = ccy / dn, nnz = ccz / dn;

    float ax = ccy * hz - ccz * hy, ay = ccz * hx - ccx * hz, az = ccx * hy - ccy * hx;
    float px = ay * ccz - az * ccy, py = az * ccx - ax * ccz, pz = ax * ccy - ay * ccx;
    float pn = fmaxf(sqrtf(px * px + py * py + pz * pz), 1e-37f);
    px /= pn; py /= pn; pz /= pn;

    float qx = py * tnz - pz * tny;
    float qy = pz * tnx - px * tnz;
    float qz = px * tny - py * tnx;
    float sinv = qx * nnx + qy * nny + qz * nnz;

    float gr = sqrtf(hx * hx + hy * hy + hz * hz);

    const int m_h = q & (MM - 1);
    const size_t rowstride = (size_t)MM * NS;
    const size_t obase = (((size_t)b * 33) * MM + m_h) * NS + sub;
    if (half == 0) out[obase + 32 * rowstride] = gr;

    // per-lane ascending sort: Batcher odd-even mergesort, min/max CEs
    #pragma unroll
    for (int p = 1; p < NS; p <<= 1) {
        #pragma unroll
        for (int k = p; k >= 1; k >>= 1) {
            #pragma unroll
            for (int j = k & (p - 1); j + k < NS; j += 2 * k) {
                #pragma unroll
                for (int i = 0; i < k; ++i) {
                    if (i + j + k < NS) {
                        int x = i + j, y = i + j + k;
                        if ((x / (2 * p)) == (y / (2 * p))) {
                            float lo = fminf(v[x], v[y]);
                            v[y] = fmaxf(v[x], v[y]);
                            v[x] = lo;
                        }
                    }
                }
            }
        }
    }

    if (half == 0) {
        #pragma unroll
        for (int ii = 0; ii < NS; ++ii)
            out[obase + (size_t)ii * rowstride] = v[ii] * sinv;
    }
}

// ---------------- fallback: verified brute-force scan (round-4) ----------------
#define CHUNKS 4
__global__ __launch_bounds__(256) void qgr_kernel(
    const float* __restrict__ xyz,
    const float* __restrict__ nxyz,
    float* __restrict__ out) {

    __shared__ float s_gx[4][NS], s_gy[4][NS], s_gz[4][NS];
    __shared__ float s_dis[4][NS][NS + 1];

    const int lane = threadIdx.x & 63;
    const int w = threadIdx.x >> 6;
    const int q = blockIdx.x * 4 + w;
    const int b = q >> 11;
    const int m = q & (MM - 1);

    const float* xb = xyz + (size_t)b * NN * 3;
    const float* nq = nxyz + (size_t)q * 3;
    const float cx = nq[0], cy = nq[1], cz = nq[2];
    const unsigned long long lmask = (1ull << lane) - 1ull;

    int cnt = 0;
    for (int base = 0; base < NN; base += 64 * CHUNKS) {
        float X[CHUNKS], Y[CHUNKS], Z[CHUNKS];
        #pragma unroll
        for (int c = 0; c < CHUNKS; ++c) {
            const float* p = xb + (size_t)(base + c * 64 + lane) * 3;
            X[c] = p[0]; Y[c] = p[1]; Z[c] = p[2];
        }
        bool in[CHUNKS];
        #pragma unroll
        for (int c = 0; c < CHUNKS; ++c) {
            float dx = __fsub_rn(cx, X[c]);
            float dy = __fsub_rn(cy, Y[c]);
            float dz = __fsub_rn(cz, Z[c]);
            float d2 = __fadd_rn(__fadd_rn(__fmul_rn(dx, dx), __fmul_rn(dy, dy)),
                                 __fmul_rn(dz, dz));
            in[c] = d2 < R2;
        }
        #pragma unroll
        for (int c = 0; c < CHUNKS; ++c) {
            unsigned long long bal = __ballot(in[c]);
            if (bal) {
                int rank = __popcll(bal & lmask);
                int slot = cnt + rank;
                if (in[c] && slot < NS) {
                    s_gx[w][slot] = X[c]; s_gy[w][slot] = Y[c]; s_gz[w][slot] = Z[c];
                }
                cnt += __popcll(bal);
            }
        }
        if (cnt >= NS) break;
    }
    __syncthreads();

    int found = cnt < NS ? cnt : NS;
    float p0x, p0y, p0z;
    if (found == 0) { p0x = xb[0]; p0y = xb[1]; p0z = xb[2]; }
    else            { p0x = s_gx[w][0]; p0y = s_gy[w][0]; p0z = s_gz[w][0]; }
    if (lane < NS && lane >= found) {
        s_gx[w][lane] = p0x; s_gy[w][lane] = p0y; s_gz[w][lane] = p0z;
    }
    __syncthreads();

    #pragma unroll
    for (int t = 0; t < 16; ++t) {
        int e = t * 64 + lane;
        int di = e >> 5, dj = e & 31;
        float dx = __fsub_rn(s_gx[w][di], s_gx[w][dj]);
        float dy = __fsub_rn(s_gy[w][di], s_gy[w][dj]);
        float dz = __fsub_rn(s_gz[w][di], s_gz[w][dj]);
        s_dis[w][di][dj] =
            sqrtf(__fadd_rn(__fadd_rn(__fmul_rn(dx, dx), __fmul_rn(dy, dy)), __fmul_rn(dz, dz)));
    }
    __syncthreads();

    {
        int i = lane & 31;
        float r[8];
        #pragma unroll
        for (int t = 0; t < 8; ++t) {
            r[t] = __fadd_rn(__fadd_rn(__fadd_rn(s_dis[w][i][t], s_dis[w][i][t + 8]),
                                        s_dis[w][i][t + 16]),
                             s_dis[w][i][t + 24]);
        }
        float mv = __fadd_rn(__fadd_rn(__fadd_rn(r[0], r[1]), __fadd_rn(r[2], r[3])),
                             __fadd_rn(__fadd_rn(r[4], r[5]), __fadd_rn(r[6], r[7])));
        int mi = i;
        #pragma unroll
        for (int off = 1; off < 64; off <<= 1) {
            float ov = __shfl_xor(mv, off);
            int oi = __shfl_xor(mi, off);
            if (ov > mv || (ov == mv && oi < mi)) { mv = ov; mi = oi; }
        }
        float tx = s_gx[w][mi], ty = s_gy[w][mi], tz = s_gz[w][mi];
        float ux = cy * tz - cz * ty, uy = cz * tx - cx * tz, uz = cx * ty - cy * tx;
        float vx = uy * cz - uz * cy, vy = uz * cx - ux * cz, vz = ux * cy - uy * cx;
        float vn = fmaxf(sqrtf(vx * vx + vy * vy + vz * vz), 1e-37f);
        float tnx = vx / vn, tny = vy / vn, tnz = vz / vn;
        float nr = sqrtf(cx * cx + cy * cy + cz * cz);
        float dn = nr + 1e-8f;
        float nnx = cx / dn, nny = cy / dn, nnz = cz / dn;
        int j = lane & 31;
        float gx = s_gx[w][j], gy = s_gy[w][j], gz = s_gz[w][j];
        float ax = cy * gz - cz * gy, ay = cz * gx - cx * gz, az = cx * gy - cy * gx;
        float px = ay * cz - az * cy, py = az * cx - ax * cz, pz = ax * cy - ay * cx;
        float pn = fmaxf(sqrtf(px * px + py * py + pz * pz), 1e-37f);
        px /= pn; py /= pn; pz /= pn;
        float qx = py * tnz - pz * tny;
        float qy = pz * tnx - px * tnz;
        float qz = px * tny - py * tnx;
        float sinv = qx * nnx + qy * nny + qz * nnz;
        float gr = sqrtf(gx * gx + gy * gy + gz * gz);
        const size_t rowstride = (size_t)MM * NS;
        const size_t obase = (((size_t)b * 33) * MM + m) * NS + j;
        if (lane < NS) out[obase + 32 * rowstride] = gr;
        float v[NS];
        #pragma unroll
        for (int ii = 0; ii < NS; ++ii) v[ii] = s_dis[w][ii][j];
        #pragma unroll
        for (int k = 2; k <= NS; k <<= 1) {
            #pragma unroll
            for (int jj = k >> 1; jj > 0; jj >>= 1) {
                #pragma unroll
                for (int ii = 0; ii < NS; ++ii) {
                    int ll = ii ^ jj;
                    if (ll > ii) {
                        bool up = ((ii & k) == 0);
                        float a = v[ii], c2 = v[ll];
                        bool sw = up ? (a > c2) : (a < c2);
                        if (sw) { v[ii] = c2; v[ll] = a; }
                    }
                }
            }
        }
        if (lane < NS) {
            #pragma unroll
            for (int ii = 0; ii < NS; ++ii)
                out[obase + (size_t)ii * rowstride] = v[ii] * sinv;
        }
    }
}

extern "C" void kernel_launch(void* const* d_in, const int* in_sizes, int n_in,
                              void* d_out, int out_size, void* d_ws, size_t ws_size,
                              hipStream_t stream) {
    (void)in_sizes; (void)n_in; (void)out_size;
    const float* xyz = (const float*)d_in[0];
    const float* nxyz = (const float*)d_in[1];
    float* out = (float*)d_out;

    if (d_ws != nullptr && ws_size >= WS_NEED) {
        char* ws = (char*)d_ws;
        int* off = (int*)ws;
        float4* pts = (float4*)(ws + WS_PTS_OFF);

        // R13: single-dispatch build, 512 blocks x 512 threads (full chip)
        k_build_part<<<512, 512, 0, stream>>>(xyz, off, pts);
        // 8192 queries, 1 per wave, 4 waves/block -> 2048 blocks
        qgr_grid_kernel<<<(BB * MM) / 4, 256, 0, stream>>>(xyz, nxyz, off, pts, out);
    } else {
        qgr_kernel<<<(BB * MM) / 4, 256, 0, stream>>>(xyz, nxyz, out);
    }
}

// Round 5
// 92.302 us; speedup vs baseline: 1.1758x; 1.1758x over previous
//
#include <hip/hip_runtime.h>

// QueryAndGroupRRI: B=4, N=16384, M=2048, nsample=32, radius=0.1
// Inputs (float32): xyz (4,16384,3), new_xyz (4,2048,3)
// Output (float32): (4, 33, 2048, 32)  [dis_sort rows 0..31, grouped_r row 32]
//
// R14: revert R13's two regressions (512x512 build doubled per-CU work;
// 1q/wave duplicated phase-2 across halves = 2x phase-2 instructions).
// Build = R12 exact (128 blocks x 1024 thr, ~20us measured). Query = R12
// 2q/wave structure with ONE change: phase 1 iterates a concatenated
// candidate stream (prefix-summed ranges, per-lane range decode via
// constant-indexed select chain) -> ~8-12 ballot rounds/wave instead of
// 18-22, tail loop eliminated. Selection keys sort by unique original idx,
// so hit-slot order changes are output-invariant.

#define BB 4
#define NN 16384
#define MM 2048
#define NS 32
#define R2 0.01f
#define GZ 20          // z slabs
#define NCELL 2000     // 10*10*20
#define CPAD 2048
#define HCAP 128       // per-query hit cap (lambda~68, +7sigma safe)

// ws layout (off table + pts; legacy offsets kept stable)
#define WS_PTS_OFF (96 * 1024)
#define WS_NEED (WS_PTS_OFF + (size_t)BB * NN * 16)

__device__ __forceinline__ int cell_of(float x, float y, float z) {
    int ci = (int)(x * 10.0f); ci = ci < 0 ? 0 : (ci > 9 ? 9 : ci);
    int cj = (int)(y * 10.0f); cj = cj < 0 ? 0 : (cj > 9 ? 9 : cj);
    int ck = (int)(z * 20.0f); ck = ck < 0 ? 0 : (ck > 19 ? 19 : ck);
    return (ci * 10 + cj) * GZ + ck;
}

// ---- build: R12 exact (128 blocks x 1024 thr; ~20us measured) ----
__global__ __launch_bounds__(1024) void k_build_part(const float* __restrict__ xyz,
                                                     int* __restrict__ off,
                                                     float4* __restrict__ pts) {
    __shared__ int hist[CPAD];    // 8 KB: counts, then running cur offsets
    __shared__ int wsum[16];

    const int b = blockIdx.x >> 5;    // 32 blocks per batch
    const int r = blockIdx.x & 31;    // 64 cells per block
    const int t = threadIdx.x;
    const int lane = t & 63, wid = t >> 6;
    const float4* __restrict__ xb4 = (const float4*)(xyz + (size_t)b * NN * 3);
    float4* __restrict__ ptsb = pts + (size_t)b * NN;

    hist[t] = 0;
    hist[t + 1024] = 0;
    __syncthreads();

    // pass 1: full-batch histogram; 4 pts/thread/iter via 3 float4 loads
    #pragma unroll
    for (int it = 0; it < 4; ++it) {
        const int f = (it * 1024 + t) * 3;
        float4 a = xb4[f];
        float4 g = xb4[f + 1];
        float4 c = xb4[f + 2];
        atomicAdd(&hist[cell_of(a.x, a.y, a.z)], 1);
        atomicAdd(&hist[cell_of(a.w, g.x, g.y)], 1);
        atomicAdd(&hist[cell_of(g.z, g.w, c.x)], 1);
        atomicAdd(&hist[cell_of(c.y, c.z, c.w)], 1);
    }
    __syncthreads();

    // exclusive scan of hist[0..2047]: 2 cells/thread, wave shfl scan
    const int v0 = hist[2 * t];
    const int v1 = hist[2 * t + 1];
    const int s = v0 + v1;
    int xs = s;
    #pragma unroll
    for (int o = 1; o < 64; o <<= 1) {
        int u = __shfl_up(xs, o);
        if (lane >= o) xs += u;
    }
    if (lane == 63) wsum[wid] = xs;
    __syncthreads();
    int pre = 0;
    #pragma unroll
    for (int i2 = 0; i2 < 16; ++i2) pre += (i2 < wid) ? wsum[i2] : 0;
    const int excl = pre + xs - s;
    hist[2 * t] = excl;               // hist becomes cur
    hist[2 * t + 1] = excl + v0;
    if (r == 0) {                     // one block per batch writes off
        off[b * CPAD + 2 * t] = excl;
        off[b * CPAD + 2 * t + 1] = excl + v0;
    }
    __syncthreads();

    // pass 2: scatter own cell range from LDS cur (no global atomics)
    const int clo = r * 64, chi = clo + 64;
    #pragma unroll
    for (int it = 0; it < 4; ++it) {
        const int f = (it * 1024 + t) * 3;
        float4 a = xb4[f];
        float4 g = xb4[f + 1];
        float4 c = xb4[f + 2];
        const int i0 = (it * 1024 + t) * 4;
        float X[4] = {a.x, a.w, g.z, c.y};
        float Y[4] = {a.y, g.x, g.w, c.z};
        float Z[4] = {a.z, g.y, c.x, c.w};
        #pragma unroll
        for (int k = 0; k < 4; ++k) {
            int cc = cell_of(X[k], Y[k], Z[k]);
            if (cc >= clo && cc < chi) {
                int pos = atomicAdd(&hist[cc], 1);
                ptsb[pos] = make_float4(X[k], Y[k], Z[k], __int_as_float(i0 + k));
            }
        }
    }
}

// ---- query: R12 2q/wave; phase 1 = concatenated-stream scan ----
__global__ __launch_bounds__(256) void qgr_grid_kernel(
    const float* __restrict__ xyz,
    const float* __restrict__ nxyz,
    const int* __restrict__ offi,
    const float4* __restrict__ pts,
    float* __restrict__ out) {

    __shared__ float4 s_hit[4][2][HCAP];   // 16 KB: hit (x,y,z,idx-bits)
    __shared__ float4 s_sel[4][2][NS];     // 4 KB: selected 32, slot order

    const int lane = threadIdx.x & 63;
    const int w = threadIdx.x >> 6;
    const int sub = lane & 31;
    const int half = lane >> 5;
    const int q0 = blockIdx.x * 8 + w * 2;     // even; q0,q0+1 share batch b
    const int b = q0 >> 11;

    const float* xb = xyz + (size_t)b * NN * 3;
    const float* nq = nxyz + (size_t)q0 * 3;
    const float cx0 = nq[0], cy0 = nq[1], cz0 = nq[2];
    const float cx1 = nq[3], cy1 = nq[4], cz1 = nq[5];
    const unsigned long long lmask = (1ull << lane) - 1ull;

    const int* offb = offi + b * CPAD;
    const float4* ptsb = pts + (size_t)b * NN;

    // ---- phase 1: full-wave scan over concatenated candidate stream ----
    int hits01[2];
    for (int tq = 0; tq < 2; ++tq) {
        const float ccx = tq ? cx1 : cx0;
        const float ccy = tq ? cy1 : cy0;
        const float ccz = tq ? cz1 : cz0;

        int ci0 = (int)(ccx * 10.0f); ci0 = ci0 < 0 ? 0 : (ci0 > 9 ? 9 : ci0);
        int cj0 = (int)(ccy * 10.0f); cj0 = cj0 < 0 ? 0 : (cj0 > 9 ? 9 : cj0);
        int ck0 = (int)(ccz * 20.0f); ck0 = ck0 < 0 ? 0 : (ck0 > 19 ? 19 : ck0);
        int zlo = ck0 > 2 ? ck0 - 2 : 0;
        int zhi = ck0 < 17 ? ck0 + 2 : 19;

        // 9 candidate columns in fixed (di,dj) order; zero-length if off-grid.
        // All rs/rl/pref accesses are constant-indexed (no scratch spill).
        int rs[9], rl[9], pref[10];
        pref[0] = 0;
        #pragma unroll
        for (int di = -1; di <= 1; ++di) {
            #pragma unroll
            for (int dj = -1; dj <= 1; ++dj) {
                const int k = (di + 1) * 3 + (dj + 1);
                int ii = ci0 + di, jj = cj0 + dj;
                bool ok = ((unsigned)ii <= 9u) && ((unsigned)jj <= 9u);
                int base2 = ok ? (ii * 10 + jj) * GZ : 0;
                int s0 = offb[base2 + zlo];
                int e0 = offb[base2 + zhi + 1];
                rs[k] = s0;
                rl[k] = ok ? (e0 - s0) : 0;
                pref[k + 1] = pref[k] + rl[k];
            }
        }
        const int T = pref[9];   // total candidates (wave-uniform)

        int hits = 0;
        // prologue: gather chunk 0 (stream pos = lane)
        float4 cur;
        bool valid = lane < T;
        {
            const int p = lane;
            int a = rs[0] + p;
            #pragma unroll
            for (int r = 1; r < 9; ++r)
                a = (p >= pref[r]) ? (rs[r] + (p - pref[r])) : a;
            cur = ptsb[valid ? a : 0];
        }
        for (int base = 0; base < T; base += 64) {
            // prefetch next chunk while processing this one (ILP)
            float4 nxt = cur;
            bool nvalid = false;
            if (base + 64 < T) {
                const int p = base + 64 + lane;
                nvalid = p < T;
                int a = rs[0] + p;
                #pragma unroll
                for (int r = 1; r < 9; ++r)
                    a = (p >= pref[r]) ? (rs[r] + (p - pref[r])) : a;
                nxt = ptsb[nvalid ? a : 0];
            }
            float dx = __fsub_rn(ccx, cur.x);
            float dy = __fsub_rn(ccy, cur.y);
            float dz = __fsub_rn(ccz, cur.z);
            float d2 = __fadd_rn(__fadd_rn(__fmul_rn(dx, dx), __fmul_rn(dy, dy)),
                                 __fmul_rn(dz, dz));
            bool hit = valid && (d2 < R2);
            unsigned long long bal = __ballot(hit);
            if (bal) {
                int rank = __popcll(bal & lmask);
                int slot = hits + rank;
                if (hit && slot < HCAP) s_hit[w][tq][slot] = cur;
                hits += __popcll(bal);
            }
            cur = nxt;
            valid = nvalid;
        }
        hits01[tq] = hits;
    }

    // ---- phase 2: each 32-lane half handles its own query ----
    const int hits = half ? hits01[1] : hits01[0];
    const int cap = hits < HCAP ? hits : HCAP;
    const float ccx = half ? cx1 : cx0;
    const float ccy = half ? cy1 : cy0;
    const float ccz = half ? cz1 : cz0;

    // 128-elem bitonic in 4 regs x 32 lanes (verified R7); key = idx<<8 | slot
    int key[4];
    #pragma unroll
    for (int r = 0; r < 4; ++r) {
        int e = r * 32 + sub;
        int idx_e = __float_as_int(s_hit[w][half][e].w);
        key[r] = (e < cap) ? ((idx_e << 8) | e) : 0x7fffffff;
    }

    #pragma unroll
    for (int k = 2; k <= 16; k <<= 1) {
        #pragma unroll
        for (int j = k >> 1; j > 0; j >>= 1) {
            bool lower = (sub & j) == 0;
            bool asc = (sub & k) == 0;
            bool keepmin = (lower == asc);
            #pragma unroll
            for (int r = 0; r < 4; ++r) {
                int p = __shfl_xor(key[r], j);
                key[r] = keepmin ? min(key[r], p) : max(key[r], p);
            }
        }
    }
    #pragma unroll
    for (int j = 16; j > 0; j >>= 1) {
        bool lower = (sub & j) == 0;
        #pragma unroll
        for (int r = 0; r < 4; ++r) {
            int p = __shfl_xor(key[r], j);
            bool asc = (r & 1) == 0;
            key[r] = (lower == asc) ? min(key[r], p) : max(key[r], p);
        }
    }
    {
        int t0 = min(key[0], key[1]); key[1] = max(key[0], key[1]); key[0] = t0;
        int t2 = max(key[2], key[3]); key[3] = min(key[2], key[3]); key[2] = t2;
    }
    #pragma unroll
    for (int j = 16; j > 0; j >>= 1) {
        bool lower = (sub & j) == 0;
        #pragma unroll
        for (int r = 0; r < 4; ++r) {
            int p = __shfl_xor(key[r], j);
            bool asc = (r & 2) == 0;
            key[r] = (lower == asc) ? min(key[r], p) : max(key[r], p);
        }
    }
    {
        int t0 = min(key[0], key[2]); key[2] = max(key[0], key[2]); key[0] = t0;
        int t1 = min(key[1], key[3]); key[3] = max(key[1], key[3]); key[1] = t1;
        t0 = min(key[0], key[1]); key[1] = max(key[0], key[1]); key[0] = t0;
        t1 = min(key[2], key[3]); key[3] = max(key[2], key[3]); key[2] = t1;
    }
    #pragma unroll
    for (int j = 16; j > 0; j >>= 1) {
        bool lower = (sub & j) == 0;
        #pragma unroll
        for (int r = 0; r < 4; ++r) {
            int p = __shfl_xor(key[r], j);
            key[r] = lower ? min(key[r], p) : max(key[r], p);
        }
    }

    // fetch selected points (smallest 32 indices, ascending), pad with slot 0
    const int found = hits < NS ? hits : NS;
    const int hbase = half << 5;
    float4 sel = make_float4(0.f, 0.f, 0.f, 0.f);
    if (sub < found) sel = s_hit[w][half][key[0] & 0xFF];
    float p0x, p0y, p0z;
    if (found == 0) { p0x = xb[0]; p0y = xb[1]; p0z = xb[2]; }
    else {
        p0x = __shfl(sel.x, hbase); p0y = __shfl(sel.y, hbase); p0z = __shfl(sel.z, hbase);
    }
    if (sub >= found) { sel.x = p0x; sel.y = p0y; sel.z = p0z; }
    const float hx = sel.x, hy = sel.y, hz = sel.z;

    // stage selected pts for broadcast reads
    s_sel[w][half][sub] = sel;

    // dis column j=sub via ds_read_b128 broadcasts (exact np op order)
    float v[NS];
    #pragma unroll
    for (int ii = 0; ii < NS; ++ii) {
        float4 B = s_sel[w][half][ii];
        float dx = __fsub_rn(B.x, hx);
        float dy = __fsub_rn(B.y, hy);
        float dz = __fsub_rn(B.z, hz);
        v[ii] = sqrtf(__fadd_rn(__fadd_rn(__fmul_rn(dx, dx), __fmul_rn(dy, dy)),
                                __fmul_rn(dz, dz)));
    }

    // row-sub sum in numpy pairwise-8 order; half-local argmax, first-occurrence
    float r8[8];
    #pragma unroll
    for (int t = 0; t < 8; ++t) {
        r8[t] = __fadd_rn(__fadd_rn(__fadd_rn(v[t], v[t + 8]), v[t + 16]), v[t + 24]);
    }
    float mv = __fadd_rn(__fadd_rn(__fadd_rn(r8[0], r8[1]), __fadd_rn(r8[2], r8[3])),
                         __fadd_rn(__fadd_rn(r8[4], r8[5]), __fadd_rn(r8[6], r8[7])));
    int mi = sub;
    #pragma unroll
    for (int off = 1; off < 32; off <<= 1) {
        float ov = __shfl_xor(mv, off);
        int oi = __shfl_xor(mi, off);
        if (ov > mv || (ov == mv && oi < mi)) { mv = ov; mi = oi; }
    }

    float4 T = s_sel[w][half][mi];
    const float tx = T.x, ty = T.y, tz = T.z;

    float ux = ccy * tz - ccz * ty, uy = ccz * tx - ccx * tz, uz = ccx * ty - ccy * tx;
    float vx = uy * ccz - uz * ccy, vy = uz * ccx - ux * ccz, vz = ux * ccy - uy * ccx;
    float vn = fmaxf(sqrtf(vx * vx + vy * vy + vz * vz), 1e-37f);
    float tnx = vx / vn, tny = vy / vn, tnz = vz / vn;

    float nrm = sqrtf(ccx * ccx + ccy * ccy + ccz * ccz);
    float dn = nrm + 1e-8f;
    float nnx = ccx / dn, nny = ccy / dn, nnz = ccz / dn;

    float ax = ccy * hz - ccz * hy, ay = ccz * hx - ccx * hz, az = ccx * hy - ccy * hx;
    float px = ay * ccz - az * ccy, py = az * ccx - ax * ccz, pz = ax * ccy - ay * ccx;
    float pn = fmaxf(sqrtf(px * px + py * py + pz * pz), 1e-37f);
    px /= pn; py /= pn; pz /= pn;

    float qx = py * tnz - pz * tny;
    float qy = pz * tnx - px * tnz;
    float qz = px * tny - py * tnx;
    float sinv = qx * nnx + qy * nny + qz * nnz;

    float gr = sqrtf(hx * hx + hy * hy + hz * hz);

    const int m_h = (q0 + half) & (MM - 1);
    const size_t rowstride = (size_t)MM * NS;
    const size_t obase = (((size_t)b * 33) * MM + m_h) * NS + sub;
    out[obase + 32 * rowstride] = gr;

    // per-lane ascending sort: Batcher odd-even mergesort, min/max CEs
    #pragma unroll
    for (int p = 1; p < NS; p <<= 1) {
        #pragma unroll
        for (int k = p; k >= 1; k >>= 1) {
            #pragma unroll
            for (int j = k & (p - 1); j + k < NS; j += 2 * k) {
                #pragma unroll
                for (int i = 0; i < k; ++i) {
                    if (i + j + k < NS) {
                        int x = i + j, y = i + j + k;
                        if ((x / (2 * p)) == (y / (2 * p))) {
                            float lo = fminf(v[x], v[y]);
                            v[y] = fmaxf(v[x], v[y]);
                            v[x] = lo;
                        }
                    }
                }
            }
        }
    }

    #pragma unroll
    for (int ii = 0; ii < NS; ++ii)
        out[obase + (size_t)ii * rowstride] = v[ii] * sinv;
}

// ---------------- fallback: verified brute-force scan (round-4) ----------------
#define CHUNKS 4
__global__ __launch_bounds__(256) void qgr_kernel(
    const float* __restrict__ xyz,
    const float* __restrict__ nxyz,
    float* __restrict__ out) {

    __shared__ float s_gx[4][NS], s_gy[4][NS], s_gz[4][NS];
    __shared__ float s_dis[4][NS][NS + 1];

    const int lane = threadIdx.x & 63;
    const int w = threadIdx.x >> 6;
    const int q = blockIdx.x * 4 + w;
    const int b = q >> 11;
    const int m = q & (MM - 1);

    const float* xb = xyz + (size_t)b * NN * 3;
    const float* nq = nxyz + (size_t)q * 3;
    const float cx = nq[0], cy = nq[1], cz = nq[2];
    const unsigned long long lmask = (1ull << lane) - 1ull;

    int cnt = 0;
    for (int base = 0; base < NN; base += 64 * CHUNKS) {
        float X[CHUNKS], Y[CHUNKS], Z[CHUNKS];
        #pragma unroll
        for (int c = 0; c < CHUNKS; ++c) {
            const float* p = xb + (size_t)(base + c * 64 + lane) * 3;
            X[c] = p[0]; Y[c] = p[1]; Z[c] = p[2];
        }
        bool in[CHUNKS];
        #pragma unroll
        for (int c = 0; c < CHUNKS; ++c) {
            float dx = __fsub_rn(cx, X[c]);
            float dy = __fsub_rn(cy, Y[c]);
            float dz = __fsub_rn(cz, Z[c]);
            float d2 = __fadd_rn(__fadd_rn(__fmul_rn(dx, dx), __fmul_rn(dy, dy)),
                                 __fmul_rn(dz, dz));
            in[c] = d2 < R2;
        }
        #pragma unroll
        for (int c = 0; c < CHUNKS; ++c) {
            unsigned long long bal = __ballot(in[c]);
            if (bal) {
                int rank = __popcll(bal & lmask);
                int slot = cnt + rank;
                if (in[c] && slot < NS) {
                    s_gx[w][slot] = X[c]; s_gy[w][slot] = Y[c]; s_gz[w][slot] = Z[c];
                }
                cnt += __popcll(bal);
            }
        }
        if (cnt >= NS) break;
    }
    __syncthreads();

    int found = cnt < NS ? cnt : NS;
    float p0x, p0y, p0z;
    if (found == 0) { p0x = xb[0]; p0y = xb[1]; p0z = xb[2]; }
    else            { p0x = s_gx[w][0]; p0y = s_gy[w][0]; p0z = s_gz[w][0]; }
    if (lane < NS && lane >= found) {
        s_gx[w][lane] = p0x; s_gy[w][lane] = p0y; s_gz[w][lane] = p0z;
    }
    __syncthreads();

    #pragma unroll
    for (int t = 0; t < 16; ++t) {
        int e = t * 64 + lane;
        int di = e >> 5, dj = e & 31;
        float dx = __fsub_rn(s_gx[w][di], s_gx[w][dj]);
        float dy = __fsub_rn(s_gy[w][di], s_gy[w][dj]);
        float dz = __fsub_rn(s_gz[w][di], s_gz[w][dj]);
        s_dis[w][di][dj] =
            sqrtf(__fadd_rn(__fadd_rn(__fmul_rn(dx, dx), __fmul_rn(dy, dy)), __fmul_rn(dz, dz)));
    }
    __syncthreads();

    {
        int i = lane & 31;
        float r[8];
        #pragma unroll
        for (int t = 0; t < 8; ++t) {
            r[t] = __fadd_rn(__fadd_rn(__fadd_rn(s_dis[w][i][t], s_dis[w][i][t + 8]),
                                        s_dis[w][i][t + 16]),
                             s_dis[w][i][t + 24]);
        }
        float mv = __fadd_rn(__fadd_rn(__fadd_rn(r[0], r[1]), __fadd_rn(r[2], r[3])),
                             __fadd_rn(__fadd_rn(r[4], r[5]), __fadd_rn(r[6], r[7])));
        int mi = i;
        #pragma unroll
        for (int off = 1; off < 64; off <<= 1) {
            float ov = __shfl_xor(mv, off);
            int oi = __shfl_xor(mi, off);
            if (ov > mv || (ov == mv && oi < mi)) { mv = ov; mi = oi; }
        }
        float tx = s_gx[w][mi], ty = s_gy[w][mi], tz = s_gz[w][mi];
        float ux = cy * tz - cz * ty, uy = cz * tx - cx * tz, uz = cx * ty - cy * tx;
        float vx = uy * cz - uz * cy, vy = uz * cx - ux * cz, vz = ux * cy - uy * cx;
        float vn = fmaxf(sqrtf(vx * vx + vy * vy + vz * vz), 1e-37f);
        float tnx = vx / vn, tny = vy / vn, tnz = vz / vn;
        float nr = sqrtf(cx * cx + cy * cy + cz * cz);
        float dn = nr + 1e-8f;
        float nnx = cx / dn, nny = cy / dn, nnz = cz / dn;
        int j = lane & 31;
        float gx = s_gx[w][j], gy = s_gy[w][j], gz = s_gz[w][j];
        float ax = cy * gz - cz * gy, ay = cz * gx - cx * gz, az = cx * gy - cy * gx;
        float px = ay * cz - az * cy, py = az * cx - ax * cz, pz = ax * cy - ay * cx;
        float pn = fmaxf(sqrtf(px * px + py * py + pz * pz), 1e-37f);
        px /= pn; py /= pn; pz /= pn;
        float qx = py * tnz - pz * tny;
        float qy = pz * tnx - px * tnz;
        float qz = px * tny - py * tnx;
        float sinv = qx * nnx + qy * nny + qz * nnz;
        float gr = sqrtf(gx * gx + gy * gy + gz * gz);
        const size_t rowstride = (size_t)MM * NS;
        const size_t obase = (((size_t)b * 33) * MM + m) * NS + j;
        if (lane < NS) out[obase + 32 * rowstride] = gr;
        float v[NS];
        #pragma unroll
        for (int ii = 0; ii < NS; ++ii) v[ii] = s_dis[w][ii][j];
        #pragma unroll
        for (int k = 2; k <= NS; k <<= 1) {
            #pragma unroll
            for (int jj = k >> 1; jj > 0; jj >>= 1) {
                #pragma unroll
                for (int ii = 0; ii < NS; ++ii) {
                    int ll = ii ^ jj;
                    if (ll > ii) {
                        bool up = ((ii & k) == 0);
                        float a = v[ii], c2 = v[ll];
                        bool sw = up ? (a > c2) : (a < c2);
                        if (sw) { v[ii] = c2; v[ll] = a; }
                    }
                }
            }
        }
        if (lane < NS) {
            #pragma unroll
            for (int ii = 0; ii < NS; ++ii)
                out[obase + (size_t)ii * rowstride] = v[ii] * sinv;
        }
    }
}

extern "C" void kernel_launch(void* const* d_in, const int* in_sizes, int n_in,
                              void* d_out, int out_size, void* d_ws, size_t ws_size,
                              hipStream_t stream) {
    (void)in_sizes; (void)n_in; (void)out_size;
    const float* xyz = (const float*)d_in[0];
    const float* nxyz = (const float*)d_in[1];
    float* out = (float*)d_out;

    if (d_ws != nullptr && ws_size >= WS_NEED) {
        char* ws = (char*)d_ws;
        int* off = (int*)ws;
        float4* pts = (float4*)(ws + WS_PTS_OFF);

        // R14: build = R12 exact (128 x 1024)
        k_build_part<<<BB * 32, 1024, 0, stream>>>(xyz, off, pts);
        // 8192 queries, 2 per wave, 4 waves/block -> 1024 blocks
        qgr_grid_kernel<<<(BB * MM) / 8, 256, 0, stream>>>(xyz, nxyz, off, pts, out);
    } else {
        qgr_kernel<<<(BB * MM) / 4, 256, 0, stream>>>(xyz, nxyz, out);
    }
}

// Round 6
// 92.220 us; speedup vs baseline: 1.1768x; 1.0009x over previous
//
#include <hip/hip_runtime.h>

// QueryAndGroupRRI: B=4, N=16384, M=2048, nsample=32, radius=0.1
// Inputs (float32): xyz (4,16384,3), new_xyz (4,2048,3)
// Output (float32): (4, 33, 2048, 32)  [dis_sort rows 0..31, grouped_r row 32]
//
// R15: non-redundant 2-dispatch build replaces R12's redundant-histogram
// single dispatch (which made 128 blocks each visit all 16K pts twice =
// 4.2M point-visits; per-block critical path ~20us). New build:
//   k_count_scan: 4 blocks x 1024 thr (1/batch) -- LDS histogram via R12's
//     verified triplet-float4 pass + R12's verified wave scan; writes off+cur.
//   k_scatter: R9's byte-identical verified scatter (256x256, global-atomic
//     cur, i&(NN-1) idx encoding).
// 131K point-visits total, ~5-7us + 1 extra boundary (~1-3us, R9<->R12 calib).
// Query kernel byte-identical to R14 (stream-compacted phase 1; 92.3us total).

#define BB 4
#define NN 16384
#define MM 2048
#define NS 32
#define R2 0.01f
#define GZ 20          // z slabs
#define NCELL 2000     // 10*10*20
#define CPAD 2048
#define HCAP 128       // per-query hit cap (lambda~68, +7sigma safe)

// ws layout: off int[4][2048] @0 | cur @32KB | (cnt retired) | pts @96KB
#define WS_CUR_OFF (32 * 1024)
#define WS_PTS_OFF (96 * 1024)
#define WS_NEED (WS_PTS_OFF + (size_t)BB * NN * 16)

__device__ __forceinline__ int cell_of(float x, float y, float z) {
    int ci = (int)(x * 10.0f); ci = ci < 0 ? 0 : (ci > 9 ? 9 : ci);
    int cj = (int)(y * 10.0f); cj = cj < 0 ? 0 : (cj > 9 ? 9 : cj);
    int ck = (int)(z * 20.0f); ck = ck < 0 ? 0 : (ck > 19 ? 19 : ck);
    return (ci * 10 + cj) * GZ + ck;
}

// ---- R15 build stage 1: fused count+scan, one block per batch ----
__global__ __launch_bounds__(1024) void k_count_scan(const float* __restrict__ xyz,
                                                     int* __restrict__ off,
                                                     int* __restrict__ cur) {
    __shared__ int hist[CPAD];    // 8 KB
    __shared__ int wsum[16];

    const int b = blockIdx.x;
    const int t = threadIdx.x;
    const int lane = t & 63, wid = t >> 6;
    const float4* __restrict__ xb4 = (const float4*)(xyz + (size_t)b * NN * 3);

    hist[t] = 0;
    hist[t + 1024] = 0;
    __syncthreads();

    // histogram: 4 pts/thread/iter via 3 float4 loads (verified R12 pass 1)
    #pragma unroll
    for (int it = 0; it < 4; ++it) {
        const int f = (it * 1024 + t) * 3;
        float4 a = xb4[f];
        float4 g = xb4[f + 1];
        float4 c = xb4[f + 2];
        atomicAdd(&hist[cell_of(a.x, a.y, a.z)], 1);
        atomicAdd(&hist[cell_of(a.w, g.x, g.y)], 1);
        atomicAdd(&hist[cell_of(g.z, g.w, c.x)], 1);
        atomicAdd(&hist[cell_of(c.y, c.z, c.w)], 1);
    }
    __syncthreads();

    // exclusive scan of hist[0..2047]: 2 cells/thread (verified R12 scan)
    const int v0 = hist[2 * t];
    const int v1 = hist[2 * t + 1];
    const int s = v0 + v1;
    int xs = s;
    #pragma unroll
    for (int o = 1; o < 64; o <<= 1) {
        int u = __shfl_up(xs, o);
        if (lane >= o) xs += u;
    }
    if (lane == 63) wsum[wid] = xs;
    __syncthreads();
    int pre = 0;
    #pragma unroll
    for (int i2 = 0; i2 < 16; ++i2) pre += (i2 < wid) ? wsum[i2] : 0;
    const int excl = pre + xs - s;
    off[b * CPAD + 2 * t] = excl;
    off[b * CPAD + 2 * t + 1] = excl + v0;
    cur[b * CPAD + 2 * t] = excl;
    cur[b * CPAD + 2 * t + 1] = excl + v0;
}

// ---- R15 build stage 2: R9's verified scatter (global-atomic cur) ----
__global__ __launch_bounds__(256) void k_scatter(const float* __restrict__ xyz,
                                                 int* __restrict__ cur,
                                                 float4* __restrict__ pts) {
    int i = blockIdx.x * 256 + threadIdx.x;   // 0..65535
    int b = i >> 14;
    const float* p = xyz + (size_t)i * 3;
    float x = p[0], y = p[1], z = p[2];
    int pos = atomicAdd(&cur[b * CPAD + cell_of(x, y, z)], 1);
    pts[(size_t)b * NN + pos] = make_float4(x, y, z, __int_as_float(i & (NN - 1)));
}

// ---- query: byte-identical to R14 (2q/wave, concatenated-stream phase 1) ----
__global__ __launch_bounds__(256) void qgr_grid_kernel(
    const float* __restrict__ xyz,
    const float* __restrict__ nxyz,
    const int* __restrict__ offi,
    const float4* __restrict__ pts,
    float* __restrict__ out) {

    __shared__ float4 s_hit[4][2][HCAP];   // 16 KB: hit (x,y,z,idx-bits)
    __shared__ float4 s_sel[4][2][NS];     // 4 KB: selected 32, slot order

    const int lane = threadIdx.x & 63;
    const int w = threadIdx.x >> 6;
    const int sub = lane & 31;
    const int half = lane >> 5;
    const int q0 = blockIdx.x * 8 + w * 2;     // even; q0,q0+1 share batch b
    const int b = q0 >> 11;

    const float* xb = xyz + (size_t)b * NN * 3;
    const float* nq = nxyz + (size_t)q0 * 3;
    const float cx0 = nq[0], cy0 = nq[1], cz0 = nq[2];
    const float cx1 = nq[3], cy1 = nq[4], cz1 = nq[5];
    const unsigned long long lmask = (1ull << lane) - 1ull;

    const int* offb = offi + b * CPAD;
    const float4* ptsb = pts + (size_t)b * NN;

    // ---- phase 1: full-wave scan over concatenated candidate stream ----
    int hits01[2];
    for (int tq = 0; tq < 2; ++tq) {
        const float ccx = tq ? cx1 : cx0;
        const float ccy = tq ? cy1 : cy0;
        const float ccz = tq ? cz1 : cz0;

        int ci0 = (int)(ccx * 10.0f); ci0 = ci0 < 0 ? 0 : (ci0 > 9 ? 9 : ci0);
        int cj0 = (int)(ccy * 10.0f); cj0 = cj0 < 0 ? 0 : (cj0 > 9 ? 9 : cj0);
        int ck0 = (int)(ccz * 20.0f); ck0 = ck0 < 0 ? 0 : (ck0 > 19 ? 19 : ck0);
        int zlo = ck0 > 2 ? ck0 - 2 : 0;
        int zhi = ck0 < 17 ? ck0 + 2 : 19;

        // 9 candidate columns in fixed (di,dj) order; zero-length if off-grid.
        // All rs/rl/pref accesses are constant-indexed (no scratch spill).
        int rs[9], rl[9], pref[10];
        pref[0] = 0;
        #pragma unroll
        for (int di = -1; di <= 1; ++di) {
            #pragma unroll
            for (int dj = -1; dj <= 1; ++dj) {
                const int k = (di + 1) * 3 + (dj + 1);
                int ii = ci0 + di, jj = cj0 + dj;
                bool ok = ((unsigned)ii <= 9u) && ((unsigned)jj <= 9u);
                int base2 = ok ? (ii * 10 + jj) * GZ : 0;
                int s0 = offb[base2 + zlo];
                int e0 = offb[base2 + zhi + 1];
                rs[k] = s0;
                rl[k] = ok ? (e0 - s0) : 0;
                pref[k + 1] = pref[k] + rl[k];
            }
        }
        const int T = pref[9];   // total candidates (wave-uniform)

        int hits = 0;
        // prologue: gather chunk 0 (stream pos = lane)
        float4 cur;
        bool valid = lane < T;
        {
            const int p = lane;
            int a = rs[0] + p;
            #pragma unroll
            for (int r = 1; r < 9; ++r)
                a = (p >= pref[r]) ? (rs[r] + (p - pref[r])) : a;
            cur = ptsb[valid ? a : 0];
        }
        for (int base = 0; base < T; base += 64) {
            // prefetch next chunk while processing this one (ILP)
            float4 nxt = cur;
            bool nvalid = false;
            if (base + 64 < T) {
                const int p = base + 64 + lane;
                nvalid = p < T;
                int a = rs[0] + p;
                #pragma unroll
                for (int r = 1; r < 9; ++r)
                    a = (p >= pref[r]) ? (rs[r] + (p - pref[r])) : a;
                nxt = ptsb[nvalid ? a : 0];
            }
            float dx = __fsub_rn(ccx, cur.x);
            float dy = __fsub_rn(ccy, cur.y);
            float dz = __fsub_rn(ccz, cur.z);
            float d2 = __fadd_rn(__fadd_rn(__fmul_rn(dx, dx), __fmul_rn(dy, dy)),
                                 __fmul_rn(dz, dz));
            bool hit = valid && (d2 < R2);
            unsigned long long bal = __ballot(hit);
            if (bal) {
                int rank = __popcll(bal & lmask);
                int slot = hits + rank;
                if (hit && slot < HCAP) s_hit[w][tq][slot] = cur;
                hits += __popcll(bal);
            }
            cur = nxt;
            valid = nvalid;
        }
        hits01[tq] = hits;
    }

    // ---- phase 2: each 32-lane half handles its own query ----
    const int hits = half ? hits01[1] : hits01[0];
    const int cap = hits < HCAP ? hits : HCAP;
    const float ccx = half ? cx1 : cx0;
    const float ccy = half ? cy1 : cy0;
    const float ccz = half ? cz1 : cz0;

    // 128-elem bitonic in 4 regs x 32 lanes (verified R7); key = idx<<8 | slot
    int key[4];
    #pragma unroll
    for (int r = 0; r < 4; ++r) {
        int e = r * 32 + sub;
        int idx_e = __float_as_int(s_hit[w][half][e].w);
        key[r] = (e < cap) ? ((idx_e << 8) | e) : 0x7fffffff;
    }

    #pragma unroll
    for (int k = 2; k <= 16; k <<= 1) {
        #pragma unroll
        for (int j = k >> 1; j > 0; j >>= 1) {
            bool lower = (sub & j) == 0;
            bool asc = (sub & k) == 0;
            bool keepmin = (lower == asc);
            #pragma unroll
            for (int r = 0; r < 4; ++r) {
                int p = __shfl_xor(key[r], j);
                key[r] = keepmin ? min(key[r], p) : max(key[r], p);
            }
        }
    }
    #pragma unroll
    for (int j = 16; j > 0; j >>= 1) {
        bool lower = (sub & j) == 0;
        #pragma unroll
        for (int r = 0; r < 4; ++r) {
            int p = __shfl_xor(key[r], j);
            bool asc = (r & 1) == 0;
            key[r] = (lower == asc) ? min(key[r], p) : max(key[r], p);
        }
    }
    {
        int t0 = min(key[0], key[1]); key[1] = max(key[0], key[1]); key[0] = t0;
        int t2 = max(key[2], key[3]); key[3] = min(key[2], key[3]); key[2] = t2;
    }
    #pragma unroll
    for (int j = 16; j > 0; j >>= 1) {
        bool lower = (sub & j) == 0;
        #pragma unroll
        for (int r = 0; r < 4; ++r) {
            int p = __shfl_xor(key[r], j);
            bool asc = (r & 2) == 0;
            key[r] = (lower == asc) ? min(key[r], p) : max(key[r], p);
        }
    }
    {
        int t0 = min(key[0], key[2]); key[2] = max(key[0], key[2]); key[0] = t0;
        int t1 = min(key[1], key[3]); key[3] = max(key[1], key[3]); key[1] = t1;
        t0 = min(key[0], key[1]); key[1] = max(key[0], key[1]); key[0] = t0;
        t1 = min(key[2], key[3]); key[3] = max(key[2], key[3]); key[2] = t1;
    }
    #pragma unroll
    for (int j = 16; j > 0; j >>= 1) {
        bool lower = (sub & j) == 0;
        #pragma unroll
        for (int r = 0; r < 4; ++r) {
            int p = __shfl_xor(key[r], j);
            key[r] = lower ? min(key[r], p) : max(key[r], p);
        }
    }

    // fetch selected points (smallest 32 indices, ascending), pad with slot 0
    const int found = hits < NS ? hits : NS;
    const int hbase = half << 5;
    float4 sel = make_float4(0.f, 0.f, 0.f, 0.f);
    if (sub < found) sel = s_hit[w][half][key[0] & 0xFF];
    float p0x, p0y, p0z;
    if (found == 0) { p0x = xb[0]; p0y = xb[1]; p0z = xb[2]; }
    else {
        p0x = __shfl(sel.x, hbase); p0y = __shfl(sel.y, hbase); p0z = __shfl(sel.z, hbase);
    }
    if (sub >= found) { sel.x = p0x; sel.y = p0y; sel.z = p0z; }
    const float hx = sel.x, hy = sel.y, hz = sel.z;

    // stage selected pts for broadcast reads
    s_sel[w][half][sub] = sel;

    // dis column j=sub via ds_read_b128 broadcasts (exact np op order)
    float v[NS];
    #pragma unroll
    for (int ii = 0; ii < NS; ++ii) {
        float4 B = s_sel[w][half][ii];
        float dx = __fsub_rn(B.x, hx);
        float dy = __fsub_rn(B.y, hy);
        float dz = __fsub_rn(B.z, hz);
        v[ii] = sqrtf(__fadd_rn(__fadd_rn(__fmul_rn(dx, dx), __fmul_rn(dy, dy)),
                                __fmul_rn(dz, dz)));
    }

    // row-sub sum in numpy pairwise-8 order; half-local argmax, first-occurrence
    float r8[8];
    #pragma unroll
    for (int t = 0; t < 8; ++t) {
        r8[t] = __fadd_rn(__fadd_rn(__fadd_rn(v[t], v[t + 8]), v[t + 16]), v[t + 24]);
    }
    float mv = __fadd_rn(__fadd_rn(__fadd_rn(r8[0], r8[1]), __fadd_rn(r8[2], r8[3])),
                         __fadd_rn(__fadd_rn(r8[4], r8[5]), __fadd_rn(r8[6], r8[7])));
    int mi = sub;
    #pragma unroll
    for (int off = 1; off < 32; off <<= 1) {
        float ov = __shfl_xor(mv, off);
        int oi = __shfl_xor(mi, off);
        if (ov > mv || (ov == mv && oi < mi)) { mv = ov; mi = oi; }
    }

    float4 T = s_sel[w][half][mi];
    const float tx = T.x, ty = T.y, tz = T.z;

    float ux = ccy * tz - ccz * ty, uy = ccz * tx - ccx * tz, uz = ccx * ty - ccy * tx;
    float vx = uy * ccz - uz * ccy, vy = uz * ccx - ux * ccz, vz = ux * ccy - uy * ccx;
    float vn = fmaxf(sqrtf(vx * vx + vy * vy + vz * vz), 1e-37f);
    float tnx = vx / vn, tny = vy / vn, tnz = vz / vn;

    float nrm = sqrtf(ccx * ccx + ccy * ccy + ccz * ccz);
    float dn = nrm + 1e-8f;
    float nnx = ccx / dn, nny = ccy / dn, nnz = ccz / dn;

    float ax = ccy * hz - ccz * hy, ay = ccz * hx - ccx * hz, az = ccx * hy - ccy * hx;
    float px = ay * ccz - az * ccy, py = az * ccx - ax * ccz, pz = ax * ccy - ay * ccx;
    float pn = fmaxf(sqrtf(px * px + py * py + pz * pz), 1e-37f);
    px /= pn; py /= pn; pz /= pn;

    float qx = py * tnz - pz * tny;
    float qy = pz * tnx - px * tnz;
    float qz = px * tny - py * tnx;
    float sinv = qx * nnx + qy * nny + qz * nnz;

    float gr = sqrtf(hx * hx + hy * hy + hz * hz);

    const int m_h = (q0 + half) & (MM - 1);
    const size_t rowstride = (size_t)MM * NS;
    const size_t obase = (((size_t)b * 33) * MM + m_h) * NS + sub;
    out[obase + 32 * rowstride] = gr;

    // per-lane ascending sort: Batcher odd-even mergesort, min/max CEs
    #pragma unroll
    for (int p = 1; p < NS; p <<= 1) {
        #pragma unroll
        for (int k = p; k >= 1; k >>= 1) {
            #pragma unroll
            for (int j = k & (p - 1); j + k < NS; j += 2 * k) {
                #pragma unroll
                for (int i = 0; i < k; ++i) {
                    if (i + j + k < NS) {
                        int x = i + j, y = i + j + k;
                        if ((x / (2 * p)) == (y / (2 * p))) {
                            float lo = fminf(v[x], v[y]);
                            v[y] = fmaxf(v[x], v[y]);
                            v[x] = lo;
                        }
                    }
                }
            }
        }
    }

    #pragma unroll
    for (int ii = 0; ii < NS; ++ii)
        out[obase + (size_t)ii * rowstride] = v[ii] * sinv;
}

// ---------------- fallback: verified brute-force scan (round-4) ----------------
#define CHUNKS 4
__global__ __launch_bounds__(256) void qgr_kernel(
    const float* __restrict__ xyz,
    const float* __restrict__ nxyz,
    float* __restrict__ out) {

    __shared__ float s_gx[4][NS], s_gy[4][NS], s_gz[4][NS];
    __shared__ float s_dis[4][NS][NS + 1];

    const int lane = threadIdx.x & 63;
    const int w = threadIdx.x >> 6;
    const int q = blockIdx.x * 4 + w;
    const int b = q >> 11;
    const int m = q & (MM - 1);

    const float* xb = xyz + (size_t)b * NN * 3;
    const float* nq = nxyz + (size_t)q * 3;
    const float cx = nq[0], cy = nq[1], cz = nq[2];
    const unsigned long long lmask = (1ull << lane) - 1ull;

    int cnt = 0;
    for (int base = 0; base < NN; base += 64 * CHUNKS) {
        float X[CHUNKS], Y[CHUNKS], Z[CHUNKS];
        #pragma unroll
        for (int c = 0; c < CHUNKS; ++c) {
            const float* p = xb + (size_t)(base + c * 64 + lane) * 3;
            X[c] = p[0]; Y[c] = p[1]; Z[c] = p[2];
        }
        bool in[CHUNKS];
        #pragma unroll
        for (int c = 0; c < CHUNKS; ++c) {
            float dx = __fsub_rn(cx, X[c]);
            float dy = __fsub_rn(cy, Y[c]);
            float dz = __fsub_rn(cz, Z[c]);
            float d2 = __fadd_rn(__fadd_rn(__fmul_rn(dx, dx), __fmul_rn(dy, dy)),
                                 __fmul_rn(dz, dz));
            in[c] = d2 < R2;
        }
        #pragma unroll
        for (int c = 0; c < CHUNKS; ++c) {
            unsigned long long bal = __ballot(in[c]);
            if (bal) {
                int rank = __popcll(bal & lmask);
                int slot = cnt + rank;
                if (in[c] && slot < NS) {
                    s_gx[w][slot] = X[c]; s_gy[w][slot] = Y[c]; s_gz[w][slot] = Z[c];
                }
                cnt += __popcll(bal);
            }
        }
        if (cnt >= NS) break;
    }
    __syncthreads();

    int found = cnt < NS ? cnt : NS;
    float p0x, p0y, p0z;
    if (found == 0) { p0x = xb[0]; p0y = xb[1]; p0z = xb[2]; }
    else            { p0x = s_gx[w][0]; p0y = s_gy[w][0]; p0z = s_gz[w][0]; }
    if (lane < NS && lane >= found) {
        s_gx[w][lane] = p0x; s_gy[w][lane] = p0y; s_gz[w][lane] = p0z;
    }
    __syncthreads();

    #pragma unroll
    for (int t = 0; t < 16; ++t) {
        int e = t * 64 + lane;
        int di = e >> 5, dj = e & 31;
        float dx = __fsub_rn(s_gx[w][di], s_gx[w][dj]);
        float dy = __fsub_rn(s_gy[w][di], s_gy[w][dj]);
        float dz = __fsub_rn(s_gz[w][di], s_gz[w][dj]);
        s_dis[w][di][dj] =
            sqrtf(__fadd_rn(__fadd_rn(__fmul_rn(dx, dx), __fmul_rn(dy, dy)), __fmul_rn(dz, dz)));
    }
    __syncthreads();

    {
        int i = lane & 31;
        float r[8];
        #pragma unroll
        for (int t = 0; t < 8; ++t) {
            r[t] = __fadd_rn(__fadd_rn(__fadd_rn(s_dis[w][i][t], s_dis[w][i][t + 8]),
                                        s_dis[w][i][t + 16]),
                             s_dis[w][i][t + 24]);
        }
        float mv = __fadd_rn(__fadd_rn(__fadd_rn(r[0], r[1]), __fadd_rn(r[2], r[3])),
                             __fadd_rn(__fadd_rn(r[4], r[5]), __fadd_rn(r[6], r[7])));
        int mi = i;
        #pragma unroll
        for (int off = 1; off < 64; off <<= 1) {
            float ov = __shfl_xor(mv, off);
            int oi = __shfl_xor(mi, off);
            if (ov > mv || (ov == mv && oi < mi)) { mv = ov; mi = oi; }
        }
        float tx = s_gx[w][mi], ty = s_gy[w][mi], tz = s_gz[w][mi];
        float ux = cy * tz - cz * ty, uy = cz * tx - cx * tz, uz = cx * ty - cy * tx;
        float vx = uy * cz - uz * cy, vy = uz * cx - ux * cz, vz = ux * cy - uy * cx;
        float vn = fmaxf(sqrtf(vx * vx + vy * vy + vz * vz), 1e-37f);
        float tnx = vx / vn, tny = vy / vn, tnz = vz / vn;
        float nr = sqrtf(cx * cx + cy * cy + cz * cz);
        float dn = nr + 1e-8f;
        float nnx = cx / dn, nny = cy / dn, nnz = cz / dn;
        int j = lane & 31;
        float gx = s_gx[w][j], gy = s_gy[w][j], gz = s_gz[w][j];
        float ax = cy * gz - cz * gy, ay = cz * gx - cx * gz, az = cx * gy - cy * gx;
        float px = ay * cz - az * cy, py = az * cx - ax * cz, pz = ax * cy - ay * cx;
        float pn = fmaxf(sqrtf(px * px + py * py + pz * pz), 1e-37f);
        px /= pn; py /= pn; pz /= pn;
        float qx = py * tnz - pz * tny;
        float qy = pz * tnx - px * tnz;
        float qz = px * tny - py * tnx;
        float sinv = qx * nnx + qy * nny + qz * nnz;
        float gr = sqrtf(gx * gx + gy * gy + gz * gz);
        const size_t rowstride = (size_t)MM * NS;
        const size_t obase = (((size_t)b * 33) * MM + m) * NS + j;
        if (lane < NS) out[obase + 32 * rowstride] = gr;
        float v[NS];
        #pragma unroll
        for (int ii = 0; ii < NS; ++ii) v[ii] = s_dis[w][ii][j];
        #pragma unroll
        for (int k = 2; k <= NS; k <<= 1) {
            #pragma unroll
            for (int jj = k >> 1; jj > 0; jj >>= 1) {
                #pragma unroll
                for (int ii = 0; ii < NS; ++ii) {
                    int ll = ii ^ jj;
                    if (ll > ii) {
                        bool up = ((ii & k) == 0);
                        float a = v[ii], c2 = v[ll];
                        bool sw = up ? (a > c2) : (a < c2);
                        if (sw) { v[ii] = c2; v[ll] = a; }
                    }
                }
            }
        }
        if (lane < NS) {
            #pragma unroll
            for (int ii = 0; ii < NS; ++ii)
                out[obase + (size_t)ii * rowstride] = v[ii] * sinv;
        }
    }
}

extern "C" void kernel_launch(void* const* d_in, const int* in_sizes, int n_in,
                              void* d_out, int out_size, void* d_ws, size_t ws_size,
                              hipStream_t stream) {
    (void)in_sizes; (void)n_in; (void)out_size;
    const float* xyz = (const float*)d_in[0];
    const float* nxyz = (const float*)d_in[1];
    float* out = (float*)d_out;

    if (d_ws != nullptr && ws_size >= WS_NEED) {
        char* ws = (char*)d_ws;
        int* off = (int*)ws;
        int* cur = (int*)(ws + WS_CUR_OFF);
        float4* pts = (float4*)(ws + WS_PTS_OFF);

        // R15: non-redundant 2-dispatch build (no memset needed)
        k_count_scan<<<BB, 1024, 0, stream>>>(xyz, off, cur);
        k_scatter<<<(BB * NN) / 256, 256, 0, stream>>>(xyz, cur, pts);
        // 8192 queries, 2 per wave, 4 waves/block -> 1024 blocks
        qgr_grid_kernel<<<(BB * MM) / 8, 256, 0, stream>>>(xyz, nxyz, off, pts, out);
    } else {
        qgr_kernel<<<(BB * MM) / 4, 256, 0, stream>>>(xyz, nxyz, out);
    }
}